// Round 1
// baseline (1380.449 us; speedup 1.0000x reference)
//
#include <hip/hip_runtime.h>
#include <cstdint>
#include <cstddef>

// ---------------------------------------------------------------------------
// JAX threefry mode: 1 = partitionable (JAX >= 0.4.36 default), 0 = original.
// If validation fails with huge absmax error, flip this to 0.
// ---------------------------------------------------------------------------
#define JAX_PARTITIONABLE 1

// ---- problem sizes (compile-time) ----
#define T_ 2048
#define OBS_ 512
#define MLP_ 1024
#define H_ 1024
#define ACT_ 16
#define H3_ 3072

// ---- workspace layout (float element offsets) ----
#define OFF_PREW 0ul
#define OFF_P1W  524288ul
#define OFF_P2W  1572864ul
#define OFF_P3W  2621440ul
#define OFF_PREB 2637824ul
#define OFF_P1B  2638848ul
#define OFF_P2B  2639872ul
#define OFF_P3B  2640896ul
#define OFF_Z    2640912ul
#define OFF_IG   4738064ul
#define OFF_ST   11029520ul
#define OFF_META 13126672ul   // int region starts here
// meta ints: counts[2048], cursors[2048], li[2048], offsets[2048], list[2048]

#define NROUNDS_FIXED 24

// ---------------------------------------------------------------------------
// threefry2x32 (JAX/XLA exact)
// ---------------------------------------------------------------------------
__host__ __device__ __forceinline__ uint32_t rotl32(uint32_t v, int d) {
  return (v << d) | (v >> (32 - d));
}
__host__ __device__ __forceinline__ void tf2x32(uint32_t k0, uint32_t k1,
                                                uint32_t x0, uint32_t x1,
                                                uint32_t& o0, uint32_t& o1) {
  uint32_t ks2 = k0 ^ k1 ^ 0x1BD11BDAu;
  x0 += k0; x1 += k1;
  // 4 rounds {13,15,26,6}
  x0 += x1; x1 = rotl32(x1, 13); x1 ^= x0;
  x0 += x1; x1 = rotl32(x1, 15); x1 ^= x0;
  x0 += x1; x1 = rotl32(x1, 26); x1 ^= x0;
  x0 += x1; x1 = rotl32(x1, 6);  x1 ^= x0;
  x0 += k1; x1 += ks2 + 1u;
  x0 += x1; x1 = rotl32(x1, 17); x1 ^= x0;
  x0 += x1; x1 = rotl32(x1, 29); x1 ^= x0;
  x0 += x1; x1 = rotl32(x1, 16); x1 ^= x0;
  x0 += x1; x1 = rotl32(x1, 24); x1 ^= x0;
  x0 += ks2; x1 += k0 + 2u;
  x0 += x1; x1 = rotl32(x1, 13); x1 ^= x0;
  x0 += x1; x1 = rotl32(x1, 15); x1 ^= x0;
  x0 += x1; x1 = rotl32(x1, 26); x1 ^= x0;
  x0 += x1; x1 = rotl32(x1, 6);  x1 ^= x0;
  x0 += k0; x1 += k1 + 3u;
  x0 += x1; x1 = rotl32(x1, 17); x1 ^= x0;
  x0 += x1; x1 = rotl32(x1, 29); x1 ^= x0;
  x0 += x1; x1 = rotl32(x1, 16); x1 ^= x0;
  x0 += x1; x1 = rotl32(x1, 24); x1 ^= x0;
  x0 += k1; x1 += ks2 + 4u;
  x0 += x1; x1 = rotl32(x1, 13); x1 ^= x0;
  x0 += x1; x1 = rotl32(x1, 15); x1 ^= x0;
  x0 += x1; x1 = rotl32(x1, 26); x1 ^= x0;
  x0 += x1; x1 = rotl32(x1, 6);  x1 ^= x0;
  x0 += ks2; x1 += k0 + 5u;
  o0 = x0; o1 = x1;
}

// XLA ErfInv32 (Giles), w = -log1p(-x*x)
__device__ __forceinline__ float erfinv_f32(float x) {
  float w = -log1pf(-x * x);
  float p;
  if (w < 5.0f) {
    w = w - 2.5f;
    p = 2.81022636e-08f;
    p = fmaf(p, w, 3.43273939e-07f);
    p = fmaf(p, w, -3.5233877e-06f);
    p = fmaf(p, w, -4.39150654e-06f);
    p = fmaf(p, w, 0.00021858087f);
    p = fmaf(p, w, -0.00125372503f);
    p = fmaf(p, w, -0.00417768164f);
    p = fmaf(p, w, 0.246640727f);
    p = fmaf(p, w, 1.50140941f);
  } else {
    w = sqrtf(w) - 3.0f;
    p = -0.000200214257f;
    p = fmaf(p, w, 0.000100950558f);
    p = fmaf(p, w, 0.00134934322f);
    p = fmaf(p, w, -0.00367342844f);
    p = fmaf(p, w, 0.00573950773f);
    p = fmaf(p, w, -0.0076224613f);
    p = fmaf(p, w, 0.00943887047f);
    p = fmaf(p, w, 1.00167406f);
    p = fmaf(p, w, 2.83297682f);
  }
  return p * x;
}

__device__ __forceinline__ float bits_to_normal(uint32_t bits) {
  const float lo = -0.99999994f;  // nextafter(-1, 0)
  float f = __uint_as_float((bits >> 9) | 0x3f800000u) - 1.0f;  // [0,1)
  float u = fmaf(f, 2.0f, lo);
  u = fmaxf(lo, u);
  return 1.41421356237f * erfinv_f32(u);  // sqrt(2) as f32
}

__device__ __forceinline__ float sigmoidf_(float x) {
  return 1.0f / (1.0f + expf(-x));
}
// mish(x) = x * tanh(softplus(x)); softplus = logaddexp(x,0) = max(x,0)+log1p(exp(-|x|))
__device__ __forceinline__ float mishf_(float x) {
  float sp = fmaxf(x, 0.0f) + log1pf(expf(-fabsf(x)));
  return x * tanhf(sp);
}

// ---------------------------------------------------------------------------
// Noise generation: dst = wm + ws * normal(key)
// ---------------------------------------------------------------------------
struct NoiseDesc {
  const float* wm; const float* ws; float* dst;
  uint32_t k0, k1, n, base;
};
struct NoiseArgs { NoiseDesc d[8]; uint32_t total; };

__global__ __launch_bounds__(256) void k_gen_noise(NoiseArgs a) {
  uint32_t idx = blockIdx.x * 256u + threadIdx.x;
  uint32_t stride = gridDim.x * 256u;
  for (; idx < a.total; idx += stride) {
    int ti = 0;
#pragma unroll
    for (int i = 1; i < 8; ++i) if (idx >= a.d[i].base) ti = i;
    NoiseDesc dd = a.d[ti];
    uint32_t j = idx - dd.base;
#if JAX_PARTITIONABLE
    uint32_t b1, b2;
    tf2x32(dd.k0, dd.k1, 0u, j, b1, b2);
    dd.dst[j] = fmaf(dd.ws[j], bits_to_normal(b1 ^ b2), dd.wm[j]);
#else
    uint32_t half = dd.n >> 1;  // j indexes pairs (j, j+half)
    uint32_t b1, b2;
    tf2x32(dd.k0, dd.k1, j, j + half, b1, b2);
    dd.dst[j] = fmaf(dd.ws[j], bits_to_normal(b1), dd.wm[j]);
    dd.dst[j + half] = fmaf(dd.ws[j + half], bits_to_normal(b2), dd.wm[j + half]);
#endif
  }
}

// ---------------------------------------------------------------------------
// fp32 GEMM: C[M,N] = A[M,K] @ W[N,K]^T + bias[N], optional mish.
// 64x64 tile, 256 threads, 4x4 micro-tile, KB=16, transposed LDS (float4 reads)
// ---------------------------------------------------------------------------
template <int ACT>
__global__ __launch_bounds__(256) void k_gemm(
    const float* __restrict__ A, const float* __restrict__ W,
    const float* __restrict__ bias, float* __restrict__ C,
    int M, int N, int K) {
  __shared__ float As[16][68];
  __shared__ float Bs[16][68];
  const int n0 = blockIdx.x * 64;
  const int m0 = blockIdx.y * 64;
  const int tid = threadIdx.x;
  const int lr = tid >> 2;          // 0..63
  const int lc = (tid & 3) * 4;     // 0,4,8,12
  const int ty = tid >> 4, tx = tid & 15;
  float acc[4][4] = {};
  for (int k0 = 0; k0 < K; k0 += 16) {
    float4 av = *(const float4*)(A + (size_t)(m0 + lr) * K + k0 + lc);
    float4 wv = make_float4(0.f, 0.f, 0.f, 0.f);
    if (n0 + lr < N) wv = *(const float4*)(W + (size_t)(n0 + lr) * K + k0 + lc);
    __syncthreads();
    As[lc + 0][lr] = av.x; As[lc + 1][lr] = av.y; As[lc + 2][lr] = av.z; As[lc + 3][lr] = av.w;
    Bs[lc + 0][lr] = wv.x; Bs[lc + 1][lr] = wv.y; Bs[lc + 2][lr] = wv.z; Bs[lc + 3][lr] = wv.w;
    __syncthreads();
#pragma unroll
    for (int kk = 0; kk < 16; ++kk) {
      float4 a = *(const float4*)&As[kk][ty * 4];
      float4 b = *(const float4*)&Bs[kk][tx * 4];
      acc[0][0] = fmaf(a.x, b.x, acc[0][0]); acc[0][1] = fmaf(a.x, b.y, acc[0][1]);
      acc[0][2] = fmaf(a.x, b.z, acc[0][2]); acc[0][3] = fmaf(a.x, b.w, acc[0][3]);
      acc[1][0] = fmaf(a.y, b.x, acc[1][0]); acc[1][1] = fmaf(a.y, b.y, acc[1][1]);
      acc[1][2] = fmaf(a.y, b.z, acc[1][2]); acc[1][3] = fmaf(a.y, b.w, acc[1][3]);
      acc[2][0] = fmaf(a.z, b.x, acc[2][0]); acc[2][1] = fmaf(a.z, b.y, acc[2][1]);
      acc[2][2] = fmaf(a.z, b.z, acc[2][2]); acc[2][3] = fmaf(a.z, b.w, acc[2][3]);
      acc[3][0] = fmaf(a.w, b.x, acc[3][0]); acc[3][1] = fmaf(a.w, b.y, acc[3][1]);
      acc[3][2] = fmaf(a.w, b.z, acc[3][2]); acc[3][3] = fmaf(a.w, b.w, acc[3][3]);
    }
  }
#pragma unroll
  for (int i = 0; i < 4; ++i) {
#pragma unroll
    for (int j = 0; j < 4; ++j) {
      int n = n0 + tx * 4 + j;
      if (n < N) {
        int m = m0 + ty * 4 + i;
        float v = acc[i][j] + bias[n];
        if (ACT) v = mishf_(v);
        C[(size_t)m * N + n] = v;
      }
    }
  }
}

// ---------------------------------------------------------------------------
// Segment-scan machinery
// ---------------------------------------------------------------------------
__global__ void k_li(const int* __restrict__ start, int* __restrict__ li,
                     int* __restrict__ counts) {
  int t = blockIdx.x * 256 + threadIdx.x;
  if (t >= T_) return;
  int l = 0, tt = t;
  while (tt > 0 && start[tt] == 0) { tt--; l++; }
  li[t] = l;
  if (t > 0) atomicAdd(&counts[l], 1);
}

__global__ __launch_bounds__(256) void k_offsets(const int* __restrict__ counts,
                                                 int* __restrict__ offsets) {
  __shared__ int a[2048], b[2048];
  int tid = threadIdx.x;
  for (int i = tid; i < 2048; i += 256) a[i] = counts[i];
  __syncthreads();
  int* cur = a; int* nxt = b;
  for (int d = 1; d < 2048; d <<= 1) {
    for (int i = tid; i < 2048; i += 256)
      nxt[i] = cur[i] + (i >= d ? cur[i - d] : 0);
    __syncthreads();
    int* t_ = cur; cur = nxt; nxt = t_;
  }
  for (int i = tid; i < 2048; i += 256)
    offsets[i] = (i == 0) ? 0 : cur[i - 1];
}

__global__ void k_scatter(const int* __restrict__ li, const int* __restrict__ offsets,
                          int* __restrict__ cursors, int* __restrict__ list) {
  int t = blockIdx.x * 256 + threadIdx.x;
  if (t <= 0 || t >= T_) return;
  int l = li[t];
  int pos = atomicAdd(&cursors[l], 1);
  list[offsets[l] + pos] = t;
}

// One scan round: for every t with local index k, compute
// hg = h_in @ whh^T (batched, tiled 32t x 32i x 3 gates) then GRU gating.
__global__ __launch_bounds__(256) void k_scan_round(
    int k, const float* __restrict__ ig, const float* __restrict__ whh,
    const float* __restrict__ gbn, const float* __restrict__ state0,
    const int* __restrict__ start, const int* __restrict__ counts,
    const int* __restrict__ offsets, const int* __restrict__ list,
    float* __restrict__ states) {
  const int cnt = counts[k];
  const bool r0 = (k == 0);
  if (!r0 && cnt == 0) return;
  int t_tiles = (cnt + 31) >> 5;
  if (r0) t_tiles += 1;           // tile 0 of round 0 = {t=0}
  const int tiles = t_tiles << 5; // x32 i-tiles
  const int off = offsets[k];

  __shared__ float Hs[16][36];
  __shared__ float Ws[16][100];
  __shared__ int tlist[32];
  const int tid = threadIdx.x;
  const int ty = tid >> 4, tx = tid & 15;

  for (int tile = blockIdx.x; tile < tiles; tile += gridDim.x) {
    const int tt = tile >> 5;
    const int it = tile & 31;
    const int i0 = it << 5;
    const bool special = r0 && (tt == 0);
    __syncthreads();
    if (tid < 32) {
      int t = -1;
      if (special) {
        if (tid == 0) t = 0;
      } else {
        int s = (r0 ? (tt - 1) : tt) * 32 + tid;
        if (s < cnt) t = list[off + s];
      }
      tlist[tid] = t;
    }
    __syncthreads();

    float acc[2][2][3];
#pragma unroll
    for (int i = 0; i < 2; ++i)
#pragma unroll
      for (int j = 0; j < 2; ++j)
#pragma unroll
        for (int g = 0; g < 3; ++g) acc[i][j][g] = 0.f;

    const bool do_gemm = special || !r0;
    if (do_gemm) {
      const float keep0 = 1.0f - (float)start[0];
      for (int k0 = 0; k0 < H_; k0 += 16) {
        // load Hs (32 t x 16 k)
        {
          int t_loc = tid >> 3;
          int c = (tid & 7) * 2;
          int t = tlist[t_loc];
          float hx = 0.f, hy = 0.f;
          if (t > 0) {
            float2 hv = *(const float2*)(states + (size_t)(t - 1) * H_ + k0 + c);
            hx = hv.x; hy = hv.y;
          } else if (t == 0) {
            hx = state0[k0 + c] * keep0;
            hy = state0[k0 + c + 1] * keep0;
          }
          Hs[c][t_loc] = hx; Hs[c + 1][t_loc] = hy;
        }
        // load Ws (96 rows x 16 k)
#pragma unroll
        for (int g = 0; g < 3; ++g) {
          int ii = tid >> 3;
          int c = (tid & 7) * 2;
          float2 wv = *(const float2*)(whh + ((size_t)(g * H_ + i0 + ii)) * H_ + k0 + c);
          Ws[c][g * 32 + ii] = wv.x; Ws[c + 1][g * 32 + ii] = wv.y;
        }
        __syncthreads();
#pragma unroll
        for (int kk = 0; kk < 16; ++kk) {
          float2 a = *(const float2*)&Hs[kk][ty * 2];
          float2 w0 = *(const float2*)&Ws[kk][tx * 2];
          float2 w1 = *(const float2*)&Ws[kk][32 + tx * 2];
          float2 w2 = *(const float2*)&Ws[kk][64 + tx * 2];
          acc[0][0][0] = fmaf(a.x, w0.x, acc[0][0][0]);
          acc[0][1][0] = fmaf(a.x, w0.y, acc[0][1][0]);
          acc[1][0][0] = fmaf(a.y, w0.x, acc[1][0][0]);
          acc[1][1][0] = fmaf(a.y, w0.y, acc[1][1][0]);
          acc[0][0][1] = fmaf(a.x, w1.x, acc[0][0][1]);
          acc[0][1][1] = fmaf(a.x, w1.y, acc[0][1][1]);
          acc[1][0][1] = fmaf(a.y, w1.x, acc[1][0][1]);
          acc[1][1][1] = fmaf(a.y, w1.y, acc[1][1][1]);
          acc[0][0][2] = fmaf(a.x, w2.x, acc[0][0][2]);
          acc[0][1][2] = fmaf(a.x, w2.y, acc[0][1][2]);
          acc[1][0][2] = fmaf(a.y, w2.x, acc[1][0][2]);
          acc[1][1][2] = fmaf(a.y, w2.y, acc[1][1][2]);
        }
        __syncthreads();
      }
    }

    // gating + state write
    const float keep0g = 1.0f - (float)start[0];
#pragma unroll
    for (int tj = 0; tj < 2; ++tj) {
      int t = tlist[ty * 2 + tj];
      if (t < 0) continue;
#pragma unroll
      for (int ij = 0; ij < 2; ++ij) {
        int i = i0 + tx * 2 + ij;
        float ir = ig[(size_t)t * H3_ + i];
        float iz = ig[(size_t)t * H3_ + H_ + i];
        float in_ = ig[(size_t)t * H3_ + 2 * H_ + i];
        float hin;
        if (k > 0) hin = states[(size_t)(t - 1) * H_ + i];
        else hin = (t == 0) ? state0[i] * keep0g : 0.0f;
        float r = sigmoidf_(ir + acc[tj][ij][0]);
        float u = sigmoidf_(iz + acc[tj][ij][1]);
        float n = tanhf(in_ + r * (acc[tj][ij][2] + gbn[i]));
        states[(size_t)t * H_ + i] = n + u * (hin - n);
      }
    }
  }
}

// Cleanup for rounds >= NROUNDS_FIXED (vanishingly unlikely): 1 WG, sequential.
__global__ __launch_bounds__(256) void k_cleanup(
    const float* __restrict__ ig, const float* __restrict__ whh,
    const float* __restrict__ gbn, const int* __restrict__ counts,
    const int* __restrict__ offsets, const int* __restrict__ list,
    float* __restrict__ states) {
  __shared__ float hbuf[H_];
  __shared__ float hg[H3_];
  const int tid = threadIdx.x;
  for (int k = NROUNDS_FIXED; k < 2048; ++k) {
    int cnt = counts[k];
    if (cnt == 0) return;
    int off = offsets[k];
    for (int s = 0; s < cnt; ++s) {
      int t = list[off + s];
      for (int i = tid; i < H_; i += 256) hbuf[i] = states[(size_t)(t - 1) * H_ + i];
      __syncthreads();
      int wv = tid >> 6, ln = tid & 63;
      for (int r = wv; r < H3_; r += 4) {
        const float* wr = whh + (size_t)r * H_;
        float sum = 0.f;
#pragma unroll 4
        for (int u = 0; u < 16; ++u) {
          int c = ln * 16 + u;
          sum = fmaf(wr[c], hbuf[c], sum);
        }
#pragma unroll
        for (int d = 32; d > 0; d >>= 1) sum += __shfl_down(sum, d, 64);
        if (ln == 0) hg[r] = sum;
      }
      __syncthreads();
      for (int i = tid; i < H_; i += 256) {
        float hin = hbuf[i];
        float r_ = sigmoidf_(ig[(size_t)t * H3_ + i] + hg[i]);
        float u_ = sigmoidf_(ig[(size_t)t * H3_ + H_ + i] + hg[H_ + i]);
        float n_ = tanhf(ig[(size_t)t * H3_ + 2 * H_ + i] + r_ * (hg[2 * H_ + i] + gbn[i]));
        states[(size_t)t * H_ + i] = n_ + u_ * (hin - n_);
      }
      __syncthreads();
    }
  }
}

__global__ void k_final(const float* __restrict__ states, float* __restrict__ out) {
  int i = blockIdx.x * 256 + threadIdx.x;
  if (i < H_) out[T_ * ACT_ + i] = states[(size_t)(T_ - 1) * H_ + i];
}

// ---------------------------------------------------------------------------
extern "C" void kernel_launch(void* const* d_in, const int* in_sizes, int n_in,
                              void* d_out, int out_size, void* d_ws, size_t ws_size,
                              hipStream_t stream) {
  const float* x      = (const float*)d_in[0];
  const float* state0 = (const float*)d_in[1];
  const int*   start  = (const int*)d_in[2];
  const float* pre_wm = (const float*)d_in[4];
  const float* pre_ws = (const float*)d_in[5];
  const float* pre_bm = (const float*)d_in[6];
  const float* pre_bs = (const float*)d_in[7];
  const float* gru_wih = (const float*)d_in[8];
  const float* gru_whh = (const float*)d_in[9];
  const float* gru_b  = (const float*)d_in[10];
  const float* gru_bn = (const float*)d_in[11];
  const float* p1_wm = (const float*)d_in[12];
  const float* p1_ws = (const float*)d_in[13];
  const float* p1_bm = (const float*)d_in[14];
  const float* p1_bs = (const float*)d_in[15];
  const float* p2_wm = (const float*)d_in[16];
  const float* p2_ws = (const float*)d_in[17];
  const float* p2_bm = (const float*)d_in[18];
  const float* p2_bs = (const float*)d_in[19];
  const float* p3_wm = (const float*)d_in[20];
  const float* p3_ws = (const float*)d_in[21];
  const float* p3_bm = (const float*)d_in[22];
  const float* p3_bs = (const float*)d_in[23];

  float* wsf = (float*)d_ws;
  float* preW = wsf + OFF_PREW;
  float* p1W  = wsf + OFF_P1W;
  float* p2W  = wsf + OFF_P2W;
  float* p3W  = wsf + OFF_P3W;
  float* preB = wsf + OFF_PREB;
  float* p1B  = wsf + OFF_P1B;
  float* p2B  = wsf + OFF_P2B;
  float* p3B  = wsf + OFF_P3B;
  float* z    = wsf + OFF_Z;
  float* igb  = wsf + OFF_IG;
  float* st   = wsf + OFF_ST;
  float* y1   = z;    // reuse (z dead after igates GEMM)
  float* y2   = igb;  // reuse (ig dead after scan)

  int* meta    = (int*)(wsf + OFF_META);
  int* counts  = meta;
  int* cursors = meta + 2048;
  int* li      = meta + 4096;
  int* offsets = meta + 6144;
  int* list    = meta + 8192;

  // ---- host: derive the 8 noise keys (split(key(7), 8)) ----
  uint32_t nk0[8], nk1[8];
#if JAX_PARTITIONABLE
  for (int i = 0; i < 8; ++i) {
    uint32_t b1, b2;
    tf2x32(0u, 7u, 0u, (uint32_t)i, b1, b2);
    nk0[i] = b1; nk1[i] = b2;
  }
#else
  {
    uint32_t o0[8], o1[8], out16[16];
    for (int i = 0; i < 8; ++i) tf2x32(0u, 7u, (uint32_t)i, (uint32_t)(8 + i), o0[i], o1[i]);
    for (int i = 0; i < 8; ++i) { out16[i] = o0[i]; out16[8 + i] = o1[i]; }
    for (int i = 0; i < 8; ++i) { nk0[i] = out16[2 * i]; nk1[i] = out16[2 * i + 1]; }
  }
#endif

  NoiseArgs na;
  const float* wms[8]  = {pre_wm, pre_bm, p1_wm, p1_bm, p2_wm, p2_bm, p3_wm, p3_bm};
  const float* wss[8]  = {pre_ws, pre_bs, p1_ws, p1_bs, p2_ws, p2_bs, p3_ws, p3_bs};
  float* dsts[8]       = {preW, preB, p1W, p1B, p2W, p2B, p3W, p3B};
  uint32_t ns[8] = {MLP_ * OBS_, MLP_, MLP_ * H_, MLP_, MLP_ * MLP_, MLP_, ACT_ * MLP_, ACT_};
  uint32_t base = 0;
  for (int i = 0; i < 8; ++i) {
    na.d[i].wm = wms[i]; na.d[i].ws = wss[i]; na.d[i].dst = dsts[i];
    na.d[i].k0 = nk0[i]; na.d[i].k1 = nk1[i]; na.d[i].n = ns[i];
    na.d[i].base = base;
#if JAX_PARTITIONABLE
    base += ns[i];
#else
    base += ns[i] >> 1;
#endif
  }
  na.total = base;

  dim3 b256(256);

  hipMemsetAsync(counts, 0, 4096 * sizeof(int), stream);  // counts + cursors
  k_gen_noise<<<dim3(4096), b256, 0, stream>>>(na);
  k_li<<<dim3(T_ / 256), b256, 0, stream>>>(start, li, counts);
  k_offsets<<<dim3(1), b256, 0, stream>>>(counts, offsets);
  k_scatter<<<dim3(T_ / 256), b256, 0, stream>>>(li, offsets, cursors, list);

  // z = mish(x @ preW^T + preB)
  k_gemm<1><<<dim3(MLP_ / 64, T_ / 64), b256, 0, stream>>>(x, preW, preB, z, T_, MLP_, OBS_);
  // ig = z @ wih^T + gru_b
  k_gemm<0><<<dim3(H3_ / 64, T_ / 64), b256, 0, stream>>>(z, gru_wih, gru_b, igb, T_, H3_, MLP_);

  // segmented GRU scan, round-parallel
  for (int k = 0; k < NROUNDS_FIXED; ++k) {
    int maxcnt = (k == 0) ? (T_ - 1) : (T_ / (k + 1));
    int tt = (maxcnt + 31) / 32 + (k == 0 ? 1 : 0);
    int tiles = tt * 32;
    int grid = tiles > 1024 ? 1024 : tiles;
    k_scan_round<<<dim3(grid), b256, 0, stream>>>(k, igb, gru_whh, gru_bn, state0,
                                                  start, counts, offsets, list, st);
  }
  k_cleanup<<<dim3(1), b256, 0, stream>>>(igb, gru_whh, gru_bn, counts, offsets, list, st);

  // post MLP
  k_gemm<1><<<dim3(MLP_ / 64, T_ / 64), b256, 0, stream>>>(st, p1W, p1B, y1, T_, MLP_, H_);
  k_gemm<1><<<dim3(MLP_ / 64, T_ / 64), b256, 0, stream>>>(y1, p2W, p2B, y2, T_, MLP_, MLP_);
  k_gemm<0><<<dim3(1, T_ / 64), b256, 0, stream>>>(y2, p3W, p3B, (float*)d_out, T_, ACT_, MLP_);

  k_final<<<dim3(4), b256, 0, stream>>>(st, (float*)d_out);
}